// Round 12
// baseline (64.483 us; speedup 1.0000x reference)
//
#include <hip/hip_runtime.h>

// EDeeperGCN: out[e] = relu(cat(x[src],x[dst]) @ W1 + b1) @ W2 + b2
// AB[n] = [x[n]@W1_top + b1 | x[n]@W1_bot]  (f16, in d_ws)
// out[e] = relu(A[src[e]] + B[dst[e]]) @ W2 + b2
//
// Both GEMMs on mfma_f32_16x16x32_f16, proven fragment map:
//   lane = 16*g + r;  A: row r, k = 32*st + 8g + j;  B: col r, same k
//   C/D (HW, m89): col = lane&15, row = (lane>>4)*4 + reg
// edge_mlp: 64 edges/wave, DEPTH-2 inline-asm gather ring (r11 mechanism,
// proven correct) -- rebalanced for occupancy: the r11 post-mortem showed a
// concurrency shortfall (~140 lines in flight vs ~500 needed), so fewer
// edges/wave + no vmem inside the ring + 2500 blocks.

typedef _Float16 f16;
typedef _Float16 f16x8 __attribute__((ext_vector_type(8)));
typedef float    f32x4 __attribute__((ext_vector_type(4)));

#define HID  128
#define TWOH 256
#define OUTD 10

// ---------------- Kernel 0: pack weight fragments ----------------
// Slot identity: for 16-col tile T = c>>4 (c = T*16 + r), slot = T*4 + st.
__global__ __launch_bounds__(256) void prep_weights(
    const float* __restrict__ W1,   // [256, 128]
    const float* __restrict__ W2,   // [128, 10]
    f16* __restrict__ W1P,          // 4096 slots x 8
    f16* __restrict__ W2P)          // 256 slots x 8
{
    const int slot = blockIdx.x * 256 + threadIdx.x;
    if (slot < 4096) {
        const int lane = slot & 63, i = slot >> 6;
        const int r = lane & 15, g = lane >> 4;
        const int T = i >> 2, st = i & 3;
        const int c = T * 16 + r;
        f16x8 v;
#pragma unroll
        for (int j = 0; j < 8; ++j) {
            const int k = st * 32 + g * 8 + j;
            const float w = (c < HID) ? W1[k * HID + c]
                                      : W1[(HID + k) * HID + (c - HID)];
            v[j] = (f16)w;
        }
        *(f16x8*)(W1P + (long)slot * 8) = v;
    } else if (slot < 4096 + 256) {
        const int s2 = slot - 4096;
        const int lane = s2 & 63, st = s2 >> 6;
        const int r = lane & 15, g = lane >> 4;
        f16x8 v;
#pragma unroll
        for (int j = 0; j < 8; ++j)
            v[j] = (r < OUTD) ? (f16)W2[(st * 32 + g * 8 + j) * OUTD + r] : (f16)0.f;
        *(f16x8*)(W2P + (long)s2 * 8) = v;
    }
}

// ---------------- Kernel 1: AB = x @ W1cat + [b1|0], f16 out, MFMA ----------------
// Block b: node tile b>>1, column half b&1 (128 cols). Wave: 32 cols (2 ct).
__global__ __launch_bounds__(256, 3) void node_AB(
    const float* __restrict__ x,    // [N, 128]
    const f16* __restrict__ W1P,    // packed fragments
    const float* __restrict__ b1,   // [128]
    f16* __restrict__ AB,           // [N, 256]
    int n_nodes)
{
    const int t = threadIdx.x;
    const int lane = t & 63;
    const int r = lane & 15, g = lane >> 4;
    const int wv = t >> 6;
    const int n0 = (blockIdx.x >> 1) * 16;
    const int ch = blockIdx.x & 1;

    const int xrow = (n0 + r < n_nodes) ? (n0 + r) : (n_nodes - 1);
    float4 xl[4][2];
#pragma unroll
    for (int st = 0; st < 4; ++st) {
        const float* xp = x + (long)xrow * HID + st * 32 + g * 8;
        xl[st][0] = *(const float4*)xp;
        xl[st][1] = *(const float4*)(xp + 4);
    }

    f16x8 w1f[2][4];
    float bias[2];
    int cc[2];
#pragma unroll
    for (int ct = 0; ct < 2; ++ct) {
        const int T = ch * 8 + wv * 2 + ct;           // 16-col tile index
        const int c = T * 16 + r;
        cc[ct] = c;
        bias[ct] = (c < HID) ? b1[c] : 0.f;
#pragma unroll
        for (int st = 0; st < 4; ++st)
            w1f[ct][st] = *(const f16x8*)(W1P + ((long)(T * 4 + st) * 64 + lane) * 8);
    }

    f32x4 acc[2] = {{0,0,0,0},{0,0,0,0}};
#pragma unroll
    for (int st = 0; st < 4; ++st) {
        f16x8 a;
        a[0] = (f16)xl[st][0].x; a[1] = (f16)xl[st][0].y;
        a[2] = (f16)xl[st][0].z; a[3] = (f16)xl[st][0].w;
        a[4] = (f16)xl[st][1].x; a[5] = (f16)xl[st][1].y;
        a[6] = (f16)xl[st][1].z; a[7] = (f16)xl[st][1].w;
#pragma unroll
        for (int ct = 0; ct < 2; ++ct)
            acc[ct] = __builtin_amdgcn_mfma_f32_16x16x32_f16(a, w1f[ct][st], acc[ct], 0, 0, 0);
    }

#pragma unroll
    for (int ct = 0; ct < 2; ++ct) {
#pragma unroll
        for (int q = 0; q < 4; ++q) {
            const int node = n0 + g * 4 + q;
            if (node < n_nodes)
                AB[(long)node * TWOH + cc[ct]] = (f16)(acc[ct][q] + bias[ct]);
        }
    }
}

// ---------------- Kernel 2: edge gather + relu + [128x10] GEMM, MFMA ----------------
// Block = 4 waves x 64 edges = 256 edges. Depth-2 inline-asm gather ring.
__global__ __launch_bounds__(256, 3) void edge_mlp(
    const f16* __restrict__ AB,     // [N, 256]
    const int* __restrict__ ei,     // [2, E]
    const f16* __restrict__ W2P,    // packed fragments
    const float* __restrict__ b2,   // [10]
    float* __restrict__ out,        // [E, 10]
    int n_edges)
{
    const int t = threadIdx.x;
    const int lane = t & 63;
    const int r = lane & 15, g = lane >> 4;
    const int wv = t >> 6;

    f16x8 w2f[4];
#pragma unroll
    for (int st = 0; st < 4; ++st)
        w2f[st] = *(const f16x8*)(W2P + ((long)st * 64 + lane) * 8);
    const float bj = b2[(r < OUTD) ? r : 0];

    const long eb = (long)blockIdx.x * 256 + wv * 64;

    int sn[4], dn[4];
#pragma unroll
    for (int it = 0; it < 4; ++it) {
        const long e = eb + it * 16 + r;
        const long ec = (e < n_edges) ? e : (n_edges - 1);
        sn[it] = ei[ec];
        dn[it] = ei[(long)n_edges + ec];
    }

    const f16x8 zt = {0, 0, 0, 0, 0, 0, 0, 0};

    if (eb + 64 <= n_edges) {
        // Force-resolve ALL compiler-issued vmem loads now, so the compiler
        // never inserts its own vmcnt() inside the hand-counted ring.
        asm volatile("" ::
            "v"(w2f[0]), "v"(w2f[1]), "v"(w2f[2]), "v"(w2f[3]), "v"(bj),
            "v"(sn[0]), "v"(sn[1]), "v"(sn[2]), "v"(sn[3]),
            "v"(dn[0]), "v"(dn[1]), "v"(dn[2]), "v"(dn[3]));

#define DECL(IT) f16x8 pa##IT##0, pa##IT##1, pa##IT##2, pa##IT##3, \
                       pc##IT##0, pc##IT##1, pc##IT##2, pc##IT##3; \
                 f32x4 acc##IT = {0, 0, 0, 0};
        DECL(0) DECL(1) DECL(2) DECL(3)

// 8 line-perfect gathers: 2 base addrs + offset:64*st immediates.
#define ISSUE(IT) { \
    const f16* _pa = AB + ((long)sn[IT] * TWOH + g * 8); \
    const f16* _pb = AB + ((long)dn[IT] * TWOH + HID + g * 8); \
    asm volatile("global_load_dwordx4 %0, %1, off"            : "=v"(pa##IT##0) : "v"(_pa)); \
    asm volatile("global_load_dwordx4 %0, %1, off offset:64"  : "=v"(pa##IT##1) : "v"(_pa)); \
    asm volatile("global_load_dwordx4 %0, %1, off offset:128" : "=v"(pa##IT##2) : "v"(_pa)); \
    asm volatile("global_load_dwordx4 %0, %1, off offset:192" : "=v"(pa##IT##3) : "v"(_pa)); \
    asm volatile("global_load_dwordx4 %0, %1, off"            : "=v"(pc##IT##0) : "v"(_pb)); \
    asm volatile("global_load_dwordx4 %0, %1, off offset:64"  : "=v"(pc##IT##1) : "v"(_pb)); \
    asm volatile("global_load_dwordx4 %0, %1, off offset:128" : "=v"(pc##IT##2) : "v"(_pb)); \
    asm volatile("global_load_dwordx4 %0, %1, off offset:192" : "=v"(pc##IT##3) : "v"(_pb)); \
}

// Hand-counted wait, tied to the buffers it guards (defs before, uses after).
#define WAITN(IT, NSTR) \
    asm volatile("s_waitcnt vmcnt(" NSTR ")" \
        : "+v"(pa##IT##0), "+v"(pa##IT##1), "+v"(pa##IT##2), "+v"(pa##IT##3), \
          "+v"(pc##IT##0), "+v"(pc##IT##1), "+v"(pc##IT##2), "+v"(pc##IT##3)); \
    __builtin_amdgcn_sched_barrier(0);

#define COMPUTE(IT) { \
    f16x8 s; \
    s = __builtin_elementwise_max(pa##IT##0 + pc##IT##0, zt); \
    acc##IT = __builtin_amdgcn_mfma_f32_16x16x32_f16(s, w2f[0], acc##IT, 0, 0, 0); \
    s = __builtin_elementwise_max(pa##IT##1 + pc##IT##1, zt); \
    acc##IT = __builtin_amdgcn_mfma_f32_16x16x32_f16(s, w2f[1], acc##IT, 0, 0, 0); \
    s = __builtin_elementwise_max(pa##IT##2 + pc##IT##2, zt); \
    acc##IT = __builtin_amdgcn_mfma_f32_16x16x32_f16(s, w2f[2], acc##IT, 0, 0, 0); \
    s = __builtin_elementwise_max(pa##IT##3 + pc##IT##3, zt); \
    acc##IT = __builtin_amdgcn_mfma_f32_16x16x32_f16(s, w2f[3], acc##IT, 0, 0, 0); \
}

        ISSUE(0) ISSUE(1)
        WAITN(0, "8") COMPUTE(0) ISSUE(2)
        WAITN(1, "8") COMPUTE(1) ISSUE(3)
        WAITN(2, "8") COMPUTE(2)
        WAITN(3, "0") COMPUTE(3)

        // epilogue: all stores after the ring (no vmem inside it)
        if (r < OUTD) {
#pragma unroll
            for (int q = 0; q < 4; ++q) {
                out[(eb +      g * 4 + q) * OUTD + r] = acc0[q] + bj;
                out[(eb + 16 + g * 4 + q) * OUTD + r] = acc1[q] + bj;
                out[(eb + 32 + g * 4 + q) * OUTD + r] = acc2[q] + bj;
                out[(eb + 48 + g * 4 + q) * OUTD + r] = acc3[q] + bj;
            }
        }
#undef DECL
#undef ISSUE
#undef WAITN
#undef COMPUTE
    } else {
        // generic tail path (unused at E = 640000)
#pragma unroll
        for (int it = 0; it < 4; ++it) {
            f32x4 acc = {0, 0, 0, 0};
#pragma unroll
            for (int st = 0; st < 4; ++st) {
                const f16x8 a = *(const f16x8*)(AB + ((long)sn[it] * TWOH + st * 32 + g * 8));
                const f16x8 c = *(const f16x8*)(AB + ((long)dn[it] * TWOH + HID + st * 32 + g * 8));
                const f16x8 s = __builtin_elementwise_max(a + c, zt);
                acc = __builtin_amdgcn_mfma_f32_16x16x32_f16(s, w2f[st], acc, 0, 0, 0);
            }
            if (r < OUTD) {
#pragma unroll
                for (int q = 0; q < 4; ++q) {
                    const long ee = eb + it * 16 + g * 4 + q;
                    if (ee < n_edges) out[ee * OUTD + r] = acc[q] + bj;
                }
            }
        }
    }
}

extern "C" void kernel_launch(void* const* d_in, const int* in_sizes, int n_in,
                              void* d_out, int out_size, void* d_ws, size_t ws_size,
                              hipStream_t stream) {
    const float* x  = (const float*)d_in[0];
    const int*   ei = (const int*)d_in[1];
    const float* W1 = (const float*)d_in[2];
    const float* b1 = (const float*)d_in[3];
    const float* W2 = (const float*)d_in[4];
    const float* b2 = (const float*)d_in[5];
    float* out = (float*)d_out;

    const int n_nodes = in_sizes[0] / HID;          // 10000
    const int n_edges = in_sizes[1] / 2;            // 640000

    f16* AB  = (f16*)d_ws;                          // [n_nodes, 256] f16 = 5.12 MB
    f16* W1P = AB + (long)n_nodes * TWOH;           // 64 KB
    f16* W2P = W1P + 4096 * 8;                      // 4 KB

    prep_weights<<<17, 256, 0, stream>>>(W1, W2, W1P, W2P);

    node_AB<<<((n_nodes + 15) / 16) * 2, 256, 0, stream>>>(x, W1P, b1, AB, n_nodes);

    edge_mlp<<<(n_edges + 255) / 256, 256, 0, stream>>>(AB, ei, W2P, b2, out, n_edges);
}